// Round 1
// baseline (465.579 us; speedup 1.0000x reference)
//
#include <hip/hip_runtime.h>

// Point2Voxel: scatter-mean of point features into a B x 64^3 voxel grid.
// Outputs (flat, in order): masked_pc[N*3], voxel_feats[B*V*32],
// voxel_counts[B*V], inst_flag[B]  -- all float32.
//
// Binning matches XLA's compiled arithmetic: `t / 0.05` canonicalized to
// `t * 20.0f` (separate f32 roundings, NO FMA -> contract(off) LOAD-BEARING).
// Evidence: R2 (f32 div) 2.36, R3 (f64 div) 2.80, R4 (mul) PASS 0.0039.
//
// R6 scheme: gather, not scatter. Per-voxel linked lists (atomicExch push)
// built in ws; one gather kernel writes every feats/counts byte EXACTLY once.
//
// R7 (this round): inst_flag was a device-wide same-cache-line store hotspot:
// ~706K per-point stores into one 32-byte region serialize at the home L2
// sector (~1-2 st/cy chip-wide ~= 150 us). Aggregate per block in LDS first;
// only <=8 global stores per block (~32K total, ~22x less hot-line traffic).

static constexpr int kNX  = 64;
static constexpr int kNYZ = 64 * 64;
static constexpr int kV   = 64 * 64 * 64;
static constexpr int kB   = 8;
static constexpr int kC   = 32;

// ---------------- fast path: linked-list gather ----------------

// Kernel A: per-point. masked_pc, validity, list push, block-aggregated
// inst_flag. NOTE: no early returns -- __syncthreads must be uniform.
__global__ void __launch_bounds__(256) p2v_build(
    const float* __restrict__ pc, const int* __restrict__ bid,
    float* __restrict__ masked_pc, int* __restrict__ head,
    int* __restrict__ nxt, float* __restrict__ inst_flag, int n)
{
#pragma clang fp contract(off) reassociate(off)
  __shared__ int sflag[kB];
  if (threadIdx.x < kB) sflag[threadIdx.x] = 0;
  __syncthreads();

  int i = blockIdx.x * blockDim.x + threadIdx.x;

  const float HALF     = (float)(0.5 * 64 * 0.05);  // 1.60000002384f
  const float INV_UNIT = 20.0f;                      // XLA: /0.05 -> *20.0f

  if (i < n) {
    float x = pc[3 * i + 0];
    float y = pc[3 * i + 1];
    float z = pc[3 * i + 2];
    int   b = bid[i];

    bool valid = (fabsf(x) <= HALF) && (fabsf(y) <= HALF) && (fabsf(z) <= HALF);

    masked_pc[3 * i + 0] = valid ? x : 0.0f;
    masked_pc[3 * i + 1] = valid ? y : 0.0f;
    masked_pc[3 * i + 2] = valid ? z : 0.0f;

    if (valid) {
      sflag[b] = 1;  // LDS, benign same-value race

      float tx = x + HALF;
      float ty = y + HALF;
      float tz = z + HALF;
      int ix = (int)(tx * INV_UNIT);
      int iy = (int)(ty * INV_UNIT);
      int iz = (int)(tz * INV_UNIT);
      ix = min(max(ix, 0), kNX - 1);
      iy = min(max(iy, 0), kNX - 1);
      iz = min(max(iz, 0), kNX - 1);

      int lin = b * kV + ix * kNYZ + iy * kNX + iz;
      nxt[i] = atomicExch(head + lin, i);  // lock-free stack push
    }
  }

  __syncthreads();
  if (threadIdx.x < kB && sflag[threadIdx.x] != 0)
    inst_flag[threadIdx.x] = 1.0f;  // benign race: same value
}

// Kernel B: gather. 8 lanes per voxel, each lane owns 4 channels (float4).
// A wave covers 8 voxels: head reads broadcast per voxel-group, feat reads
// and feats/counts writes fully coalesced.
__global__ void __launch_bounds__(256) p2v_gather(
    const float* __restrict__ feat, const int* __restrict__ head,
    const int* __restrict__ nxt, float* __restrict__ voxel_feats,
    float* __restrict__ voxel_counts)
{
#pragma clang fp contract(off) reassociate(off)
  int gid = blockIdx.x * blockDim.x + threadIdx.x;  // < B*V*8
  int v  = gid >> 3;
  int c4 = (gid & 7) * 4;
  if (v >= kB * kV) return;

  float4 sum = make_float4(0.f, 0.f, 0.f, 0.f);
  int cnt = 0;
  int h = head[v];
  while (h >= 0) {
    const float4 f = *(const float4*)(feat + (size_t)h * kC + c4);
    sum.x += f.x; sum.y += f.y; sum.z += f.z; sum.w += f.w;
    ++cnt;
    h = nxt[h];
  }

  if (cnt >= 2) {
    double dc = (double)cnt;  // IEEE f32-equivalent quotient via double
    sum.x = (float)((double)sum.x / dc);
    sum.y = (float)((double)sum.y / dc);
    sum.z = (float)((double)sum.z / dc);
    sum.w = (float)((double)sum.w / dc);
  }
  *(float4*)(voxel_feats + (size_t)v * kC + c4) = sum;

  if (c4 == 0) voxel_counts[v] = (float)cnt;
}

// ---------------- fallback path (ws too small): R4/R5 atomic scheme --------

__global__ void __launch_bounds__(256) p2v_main_fb(
    const float* __restrict__ pc, const float* __restrict__ feat,
    const int* __restrict__ bid, float* __restrict__ masked_pc,
    float* __restrict__ voxel_feats, float* __restrict__ voxel_counts,
    float* __restrict__ inst_flag, int n)
{
#pragma clang fp contract(off) reassociate(off)
  int i = blockIdx.x * blockDim.x + threadIdx.x;
  if (i >= n) return;
  const float HALF = (float)(0.5 * 64 * 0.05);
  const float INV_UNIT = 20.0f;
  float x = pc[3 * i + 0], y = pc[3 * i + 1], z = pc[3 * i + 2];
  bool valid = (fabsf(x) <= HALF) && (fabsf(y) <= HALF) && (fabsf(z) <= HALF);
  masked_pc[3 * i + 0] = valid ? x : 0.0f;
  masked_pc[3 * i + 1] = valid ? y : 0.0f;
  masked_pc[3 * i + 2] = valid ? z : 0.0f;
  if (!valid) return;
  int ix = (int)((x + HALF) * INV_UNIT);
  int iy = (int)((y + HALF) * INV_UNIT);
  int iz = (int)((z + HALF) * INV_UNIT);
  ix = min(max(ix, 0), kNX - 1);
  iy = min(max(iy, 0), kNX - 1);
  iz = min(max(iz, 0), kNX - 1);
  int b = bid[i];
  size_t lin = (size_t)b * kV + (size_t)(ix * kNYZ + iy * kNX + iz);
  atomicAdd(voxel_counts + lin, 1.0f);
  inst_flag[b] = 1.0f;
  float* dst = voxel_feats + lin * kC;
  const float* src = feat + (size_t)i * kC;
#pragma unroll
  for (int c = 0; c < kC; ++c) atomicAdd(dst + c, src[c]);
}

__global__ void __launch_bounds__(256) p2v_finalize_fb(
    float* __restrict__ voxel_feats, const float* __restrict__ voxel_counts)
{
#pragma clang fp contract(off) reassociate(off)
  int v = blockIdx.x * blockDim.x + threadIdx.x;
  if (v >= kB * kV) return;
  float c = voxel_counts[v];
  if (c >= 2.0f) {
    float* p = voxel_feats + (size_t)v * kC;
#pragma unroll
    for (int k = 0; k < kC; ++k) p[k] = (float)((double)p[k] / (double)c);
  }
}

// ---------------------------------------------------------------------------

extern "C" void kernel_launch(void* const* d_in, const int* in_sizes, int n_in,
                              void* d_out, int out_size, void* d_ws, size_t ws_size,
                              hipStream_t stream) {
  const float* pc   = (const float*)d_in[0];
  const float* feat = (const float*)d_in[1];
  const int*   bid  = (const int*)d_in[2];
  float* out = (float*)d_out;

  int n = in_sizes[0] / 3;

  float* masked_pc    = out;
  float* voxel_feats  = out + (size_t)3 * n;
  float* voxel_counts = voxel_feats + (size_t)kB * kV * kC;
  float* inst_flag    = voxel_counts + (size_t)kB * kV;

  const int block = 256;
  size_t need = (size_t)kB * kV * sizeof(int) + (size_t)n * sizeof(int);

  if (ws_size >= need) {
    // Fast path: linked-list gather.
    int* head = (int*)d_ws;              // B*V ints (8 MB)
    int* nxt  = head + (size_t)kB * kV;  // n ints (4 MB)

    // head := -1 (0xFF bytes); inst_flag := 0 (only outputs not written
    // unconditionally by a kernel).
    hipMemsetAsync(head, 0xFF, (size_t)kB * kV * sizeof(int), stream);
    hipMemsetAsync(inst_flag, 0, kB * sizeof(float), stream);

    p2v_build<<<(n + block - 1) / block, block, 0, stream>>>(
        pc, bid, masked_pc, head, nxt, inst_flag, n);

    long long ng = (long long)kB * kV * 8;  // 8 lanes per voxel
    p2v_gather<<<(int)((ng + block - 1) / block), block, 0, stream>>>(
        feat, head, nxt, voxel_feats, voxel_counts);
  } else {
    // Fallback: proven R5 atomic scheme (needs no ws).
    size_t tail_floats = (size_t)kB * kV * kC + (size_t)kB * kV + kB;
    hipMemsetAsync(voxel_feats, 0, tail_floats * sizeof(float), stream);
    p2v_main_fb<<<(n + block - 1) / block, block, 0, stream>>>(
        pc, feat, bid, masked_pc, voxel_feats, voxel_counts, inst_flag, n);
    int nv = kB * kV;
    p2v_finalize_fb<<<(nv + block - 1) / block, block, 0, stream>>>(
        voxel_feats, voxel_counts);
  }
}